// Round 8
// baseline (83.246 us; speedup 1.0000x reference)
//
#include <hip/hip_runtime.h>
#include <math.h>

// Problem constants (match reference setup_inputs)
#define NN 4096
#define MM 128
#define QQ 64
#define DD 128
#define CC (MM * QQ)          // 8192 gemm "columns" (flattened m,q)
#define GRIDN 512             // persistent grid: 2 blocks/CU guaranteed resident

typedef float f32x4 __attribute__((ext_vector_type(4)));
typedef float f32x2 __attribute__((ext_vector_type(2)));
typedef int   i32x4 __attribute__((ext_vector_type(4)));
typedef int   i32x8 __attribute__((ext_vector_type(8)));

#define AS1 __attribute__((address_space(1)))
#define AS3 __attribute__((address_space(3)))

// Self-resetting, fence-free grid barrier in device globals (zero-init at
// module load). Cumulative counters: block derives its barrier instance from
// its sub-counter ticket (prev>>6) and spins until master >= 8*(instance+1).
// RELAXED agent-scope ops (coherence from scope, no per-poll invalidates);
// cross-phase visibility = bypass stores + vmcnt drain at __syncthreads.
// Contract verified rounds 2-7.
__device__ unsigned g_sub[8 * 16];   // 8 sub-counters, 64 B apart
__device__ unsigned g_master;

__device__ __forceinline__ void grid_barrier(int bid)
{
    __syncthreads();                       // drains vmcnt: stores are at MALL
    asm volatile("" ::: "memory");
    if (threadIdx.x == 0) {
        unsigned* sub = &g_sub[(bid & 7) * 16];
        const unsigned prev =
            __hip_atomic_fetch_add(sub, 1u, __ATOMIC_RELAXED, __HIP_MEMORY_SCOPE_AGENT);
        const unsigned tgt = ((prev >> 6) + 1u) << 3;   // 8*(instance+1)
        if ((prev & 63u) == 63u)
            __hip_atomic_fetch_add(&g_master, 1u, __ATOMIC_RELAXED, __HIP_MEMORY_SCOPE_AGENT);
        while ((int)(__hip_atomic_load(&g_master, __ATOMIC_RELAXED,
                                       __HIP_MEMORY_SCOPE_AGENT) - tgt) < 0)
            __builtin_amdgcn_s_sleep(8);
    }
    asm volatile("" ::: "memory");
    __syncthreads();
}

// Round-8 change: 512 threads/block (8 waves), wave tile 32n x 64c.
// Rationale: rounds 5-7 showed ~28us of latency stall with only 2 waves/SIMD
// (TLP-starved: both waves in the same block, same barriers -> nothing to run
// during ~900cy staging windows). 8 waves/block + 2 blocks/CU = 4 waves/SIMD
// and each wave's critical path (MFMAs, exps) halves.
__global__ __launch_bounds__(512, 4)
void kde_fused(const float* __restrict__ A, const float* __restrict__ B,
               const float* __restrict__ var,
               unsigned char* __restrict__ A8, unsigned char* __restrict__ B8,
               float* __restrict__ a2w, float* __restrict__ b2w,
               float* __restrict__ dpc,   // [MM][NN] transposed densities (ws)
               float* __restrict__ out)   // [NN][MM]
{
    __shared__ unsigned char Bs[128 * DD];        // 16 KB, staged once per block
    __shared__ unsigned char As[2][128 * DD];     // 32 KB, double-buffered
    __shared__ float a2s[2][128];
    __shared__ float b2s[128];
    // pad LDS past 160/3 KB so at most 2 blocks fit per CU (uniform residency
    // under the grid barriers). Kept alive by one volatile store.
    __shared__ unsigned char lds_pad[4096];

    const int bid = blockIdx.x;
    const int t = threadIdx.x, w = t >> 6, lane = t & 63;

    if (t == 0) { volatile unsigned char* p = lds_pad; p[0] = 0; }

    // ---------------- Phase A: convert + exact fp32 squared norms ----------------
    // 24 rows per block: pass0 = 16 rows (all threads), pass1 = 8 rows (t<256).
    {
        const int l32 = t & 31;
        #pragma unroll
        for (int p = 0; p < 2; ++p) {
            if (p == 1 && t >= 256) break;
            const int row = bid * 24 + p * 16 + (t >> 5);
            const float* src; unsigned char* dst; float* nrm;
            if (row < NN) { src = A + (size_t)row * DD; dst = A8 + (size_t)row * DD; nrm = a2w + row; }
            else {
                const int r = row - NN;
                src = B + (size_t)r * DD; dst = B8 + (size_t)r * DD; nrm = b2w + r;
            }
            const float4 v = ((const float4*)src)[l32];
            int pk = __builtin_amdgcn_cvt_pk_fp8_f32(v.x, v.y, 0, false);   // bytes 0,1
            pk     = __builtin_amdgcn_cvt_pk_fp8_f32(v.z, v.w, pk, true);   // bytes 2,3
            __hip_atomic_store((unsigned int*)dst + l32, (unsigned int)pk,
                               __ATOMIC_RELAXED, __HIP_MEMORY_SCOPE_AGENT);
            float s = v.x * v.x + v.y * v.y + v.z * v.z + v.w * v.w;
            #pragma unroll
            for (int mth = 16; mth > 0; mth >>= 1) s += __shfl_xor(s, mth, 64);  // 32-group
            if (l32 == 0)
                __hip_atomic_store(nrm, s, __ATOMIC_RELAXED, __HIP_MEMORY_SCOPE_AGENT);
        }
    }

    grid_barrier(bid);

    // ---------------- Phase B: densities (4 tiles/block, fixed cb) ----------------
    const int xcd = bid & 7;
    const int cb  = (xcd << 3) | ((bid >> 3) & 7);   // 0..63
    const int nb0 = bid >> 6;                        // 0..7
    const int c0  = cb * 128;
    {
        // stage B (once) + b2s + As[0] + a2s[0]; 8 waves, 2 chunks each of 1024
        {
            const unsigned char* Bb = B8 + (size_t)c0 * DD;
            #pragma unroll
            for (int i = 0; i < 2; ++i) {
                const int slot = w * 128 + i * 64 + lane;            // 0..1023
                const int r = slot >> 3, c16 = slot & 7, scb = c16 ^ (r & 7);
                __builtin_amdgcn_global_load_lds(
                    (const AS1 unsigned int*)(Bb + r * DD + scb * 16),
                    (AS3 unsigned int*)&Bs[slot * 16], 16, 0, 0);
            }
            if (w >= 6)
                __builtin_amdgcn_global_load_lds(
                    (const AS1 unsigned int*)(b2w + c0 + (w - 6) * 64 + lane),
                    (AS3 unsigned int*)&b2s[(w - 6) * 64 + lane], 4, 0, 0);
            const int n0 = nb0 * 128;
            const unsigned char* Ab = A8 + (size_t)n0 * DD;
            #pragma unroll
            for (int i = 0; i < 2; ++i) {
                const int slot = w * 128 + i * 64 + lane;
                const int r = slot >> 3, c16 = slot & 7, scb = c16 ^ (r & 7);
                __builtin_amdgcn_global_load_lds(
                    (const AS1 unsigned int*)(Ab + r * DD + scb * 16),
                    (AS3 unsigned int*)&As[0][slot * 16], 16, 0, 0);
            }
            if (w < 2)
                __builtin_amdgcn_global_load_lds(
                    (const AS1 unsigned int*)(a2w + n0 + w * 64 + lane),
                    (AS3 unsigned int*)&a2s[0][w * 64 + lane], 4, 0, 0);
        }
        __syncthreads();   // drains vmcnt(0) incl. global_load_lds

        // 8 waves: wy = w>>1 (4 n-strips of 32), wx = w&1 (2 c-strips of 64)
        const int l15 = lane & 15, q = lane >> 4, xr = l15 & 7;
        const int wy = w >> 1, wx = w & 1;
        const int rbase = wy * 32, cbase = wx * 64;
        const int m = (cb << 1) + wx;
        const float hinvL = (0.5f / var[0]) * 1.44269504088896f;  // 0.5/var * log2(e)
        const float h2L   = hinvL + hinvL;

        // hoist c-side factors AND B-fragments out of the t4 loop
        f32x4 nbh[4];
        i32x8 b8v[4];
        #pragma unroll
        for (int jc = 0; jc < 4; ++jc) {
            const f32x4 bv = *(const f32x4*)&b2s[cbase + jc * 16 + q * 4];
            nbh[jc] = -bv * hinvL;
            const int ro = (cbase + jc * 16 + l15) * DD;
            const i32x4 lo = *(const i32x4*)&Bs[ro + (((q << 1) | 0) ^ xr) * 16];
            const i32x4 hi = *(const i32x4*)&Bs[ro + (((q << 1) | 1) ^ xr) * 16];
            #pragma unroll
            for (int e = 0; e < 4; ++e) { b8v[jc][e] = lo[e]; b8v[jc][4 + e] = hi[e]; }
        }

        float myv[4];   // deferred dpc values (statically indexed; lane<32 only)

        #pragma unroll
        for (int t4 = 0; t4 < 4; ++t4) {
            const int buf = t4 & 1;

            // prefetch next A-tile into the other buffer (hidden under MFMA)
            if (t4 < 3) {
                const int n0n = (nb0 + 8 * (t4 + 1)) * 128;
                const unsigned char* Ab = A8 + (size_t)n0n * DD;
                #pragma unroll
                for (int i = 0; i < 2; ++i) {
                    const int slot = w * 128 + i * 64 + lane;
                    const int r = slot >> 3, c16 = slot & 7, scb = c16 ^ (r & 7);
                    __builtin_amdgcn_global_load_lds(
                        (const AS1 unsigned int*)(Ab + r * DD + scb * 16),
                        (AS3 unsigned int*)&As[buf ^ 1][slot * 16], 16, 0, 0);
                }
                if (w < 2)
                    __builtin_amdgcn_global_load_lds(
                        (const AS1 unsigned int*)(a2w + n0n + w * 64 + lane),
                        (AS3 unsigned int*)&a2s[buf ^ 1][w * 64 + lane], 4, 0, 0);
            }

            // A fragments: lane holds A[rbase+i*16+l15][q*32 .. q*32+31], i<2
            i32x8 a8[2];
            #pragma unroll
            for (int i = 0; i < 2; ++i) {
                const int ro = (rbase + i * 16 + l15) * DD;
                const i32x4 lo = *(const i32x4*)&As[buf][ro + (((q << 1) | 0) ^ xr) * 16];
                const i32x4 hi = *(const i32x4*)&As[buf][ro + (((q << 1) | 1) ^ xr) * 16];
                #pragma unroll
                for (int e = 0; e < 4; ++e) { a8[i][e] = lo[e]; a8[i][4 + e] = hi[e]; }
            }

            // Swapped operands: D[row=c][col=n] -> c-reduction is in-register.
            // Pure-register MFMA cluster (8 MFMAs).
            f32x4 acc[4][2] = {};
            __builtin_amdgcn_s_setprio(1);
            #pragma unroll
            for (int jc = 0; jc < 4; ++jc)
                #pragma unroll
                for (int i = 0; i < 2; ++i)
                    acc[jc][i] = __builtin_amdgcn_mfma_scale_f32_16x16x128_f8f6f4(
                                    b8v[jc], a8[i], acc[jc][i],
                                    0, 0,          // cbsz=0 (fp8), blgp=0 (fp8)
                                    0, 127,        // scale_a = 1.0
                                    0, 127);       // scale_b = 1.0
            __builtin_amdgcn_s_setprio(0);

            // epilogue: dens = exp2(log2e*(2ab - a2 - b2)*0.5/var);
            // 16 c lane-local -> 2 partial chains + 4-way over q (2 shfl).
            float sums[2];
            #pragma unroll
            for (int i = 0; i < 2; ++i) {
                const float aih = a2s[buf][rbase + i * 16 + l15] * hinvL;
                float s0 = 0.f, s1 = 0.f;
                #pragma unroll
                for (int jc = 0; jc < 4; jc += 2) {
                    #pragma unroll
                    for (int r = 0; r < 4; ++r) {
                        s0 += __builtin_amdgcn_exp2f(fmaf(h2L, acc[jc][i][r],     nbh[jc][r]     - aih));
                        s1 += __builtin_amdgcn_exp2f(fmaf(h2L, acc[jc + 1][i][r], nbh[jc + 1][r] - aih));
                    }
                }
                float s = s0 + s1;
                s += __shfl_xor(s, 16, 64);
                s += __shfl_xor(s, 32, 64);
                sums[i] = s;   // full 64-col sum for n = rbase + i*16 + l15
            }
            // lanes 0..31 own n = rbase + (lane&31): q==0 -> sums[0], q==1 -> sums[1]
            myv[t4] = (q & 1) ? sums[1] : sums[0];

            __syncthreads();   // As[buf^1] ready; As[buf]/a2s[buf] reads done
        }

        // deferred dpc stores (drained once, by barrier-2's syncthreads)
        if (lane < 32) {
            #pragma unroll
            for (int t4 = 0; t4 < 4; ++t4) {
                const int n0 = (nb0 + 8 * t4) * 128;
                __hip_atomic_store(&dpc[(size_t)m * NN + n0 + rbase + (lane & 31)], myv[t4],
                                   __ATOMIC_RELAXED, __HIP_MEMORY_SCOPE_AGENT);
            }
        }
    }

    grid_barrier(bid);

    // ---------------- Phase C: normalize, 8 n per block (512 threads) ----------------
    {
        const int n0c = bid * 8;
        float* tile = (float*)&As[0][0];   // reuse: [128][9] floats, padded
        float* rden = b2s;                 // reuse: 8 floats
        const int mr = t >> 2, quarter = t & 3;       // 128 m x 4 quarters
        const f32x2 v = *(const f32x2*)&dpc[(size_t)mr * NN + n0c + quarter * 2];
        tile[mr * 9 + quarter * 2]     = v[0];
        tile[mr * 9 + quarter * 2 + 1] = v[1];
        __syncthreads();
        if (t < 8) {
            float s = 0.f;
            #pragma unroll 8
            for (int mm = 0; mm < MM; ++mm) s += tile[mm * 9 + t];  // m ascending
            rden[t] = 1.f / (s + 1e-10f);
        }
        __syncthreads();
        const int j = t >> 6, mq = (t & 63) * 2;      // 8 n x 64 threads x 2 m
        const float r = rden[j];
        f32x2 o;
        o[0] = tile[mq * 9 + j] * r;
        o[1] = tile[(mq + 1) * 9 + j] * r;
        *(f32x2*)&out[(size_t)(n0c + j) * MM + mq] = o;   // coalesced f32x2
    }
}

extern "C" void kernel_launch(void* const* d_in, const int* in_sizes, int n_in,
                              void* d_out, int out_size, void* d_ws, size_t ws_size,
                              hipStream_t stream) {
    const float* A   = (const float*)d_in[0];   // [4096][128]
    const float* B   = (const float*)d_in[1];   // [128][64][128] = [8192][128]
    const float* var = (const float*)d_in[2];   // [1]
    float* out = (float*)d_out;                 // [4096][128]

    unsigned char* A8 = (unsigned char*)d_ws;            // 512 KB
    unsigned char* B8 = A8 + (size_t)NN * DD;            // 1 MB
    float* a2  = (float*)(B8 + (size_t)CC * DD);         // 16 KB
    float* b2  = a2 + NN;                                // 32 KB
    float* dpc = b2 + CC;                                // 2 MB, [MM][NN]

    // single graph node: barrier counters are self-resetting device globals
    kde_fused<<<GRIDN, 512, 0, stream>>>(A, B, var, A8, B8, a2, b2, dpc, out);
}

// Round 9
// 76.761 us; speedup vs baseline: 1.0845x; 1.0845x over previous
//
#include <hip/hip_runtime.h>
#include <math.h>

// Problem constants (match reference setup_inputs)
#define NN 4096
#define MM 128
#define QQ 64
#define DD 128
#define CC (MM * QQ)          // 8192 gemm "columns" (flattened m,q)

typedef float f32x4 __attribute__((ext_vector_type(4)));
typedef int   i32x4 __attribute__((ext_vector_type(4)));
typedef int   i32x8 __attribute__((ext_vector_type(8)));

#define AS1 __attribute__((address_space(1)))
#define AS3 __attribute__((address_space(3)))

// ---- prep: fp32 -> fp8 e4m3 (OCP) convert + exact fp32 squared norms ----
// (verbatim round-0 kernel: plain stores; cross-kernel visibility from the
// dispatch boundary; outputs L2-resident for the dens kernel)
__global__ __launch_bounds__(256)
void prep_kernel(const float* __restrict__ A, const float* __restrict__ B,
                 unsigned char* __restrict__ A8, unsigned char* __restrict__ B8,
                 float* __restrict__ a2, float* __restrict__ b2)
{
    const int row = blockIdx.x * 8 + (threadIdx.x >> 5);    // 0..12287
    const int l32 = threadIdx.x & 31;
    const float* src;
    unsigned char* dst;
    float* nrm;
    if (row < NN) { src = A + (size_t)row * DD; dst = A8 + (size_t)row * DD; nrm = a2 + row; }
    else {
        int r = row - NN;
        src = B + (size_t)r * DD; dst = B8 + (size_t)r * DD; nrm = b2 + r;
    }
    float4 v = ((const float4*)src)[l32];
    int pk = __builtin_amdgcn_cvt_pk_fp8_f32(v.x, v.y, 0, false);   // bytes 0,1
    pk     = __builtin_amdgcn_cvt_pk_fp8_f32(v.z, v.w, pk, true);   // bytes 2,3
    ((int*)dst)[l32] = pk;
    float s = v.x * v.x + v.y * v.y + v.z * v.z + v.w * v.w;
    #pragma unroll
    for (int m = 16; m > 0; m >>= 1) s += __shfl_xor(s, m, 64);  // stays in 32-group
    if (l32 == 0) *nrm = s;
}

// ---- dens: one 128n x 128c tile per block, 2048 blocks (independent phases:
// blocks at random pipeline positions hide each other's staging/exp latency
// -- the phase diversity the persistent-fused design lacked, rounds 5-8).
// Swapped-operand MFMA: D[row=c][col=n] puts the c-reduction in-register
// (15 adds + 2 shfl_xor instead of 64 shfls + LDS round-trip). Verified
// numerics from rounds 5-7.
__global__ __launch_bounds__(256, 3)
void kde_dens_kernel(const unsigned char* __restrict__ A8,   // [NN][DD] fp8
                     const unsigned char* __restrict__ B8,   // [CC][DD] fp8
                     const float* __restrict__ var,
                     const float* __restrict__ a2w,          // [NN]
                     const float* __restrict__ b2w,          // [CC]
                     float* __restrict__ dpc)                // [MM][NN] transposed
{
    __shared__ unsigned char As[128 * DD];   // 16 KB
    __shared__ unsigned char Bs[128 * DD];   // 16 KB
    __shared__ float a2s[128];
    __shared__ float b2s[128];

    // XCD swizzle: XCD x owns cb in [8x, 8x+8) -> B-tile L2 reuse within XCD
    const int lin = blockIdx.x;                 // 0..2047
    const int xcd = lin & 7;
    const int loc = lin >> 3;                   // 0..255
    const int cb  = (xcd << 3) | (loc & 7);     // 0..63
    const int nb  = loc >> 3;                   // 0..31
    const int n0  = nb * 128;
    const int c0  = cb * 128;

    const int t = threadIdx.x, w = t >> 6, lane = t & 63;

    // ---- async staging: 1024 A-chunks + 1024 B-chunks (16 B each) ----
    {
        const unsigned char* Ab = A8 + (size_t)n0 * DD;
        const unsigned char* Bb = B8 + (size_t)c0 * DD;
        #pragma unroll
        for (int i = 0; i < 4; ++i) {
            const int slot = w * 256 + i * 64 + lane;   // 0..1023
            const int r = slot >> 3, c16 = slot & 7, scb = c16 ^ (r & 7);
            __builtin_amdgcn_global_load_lds(
                (const AS1 unsigned int*)(Ab + r * DD + scb * 16),
                (AS3 unsigned int*)&As[slot * 16], 16, 0, 0);
            __builtin_amdgcn_global_load_lds(
                (const AS1 unsigned int*)(Bb + r * DD + scb * 16),
                (AS3 unsigned int*)&Bs[slot * 16], 16, 0, 0);
        }
        if (t < 128)        a2s[t]       = a2w[n0 + t];
        else                b2s[t - 128] = b2w[c0 + (t - 128)];
    }
    __syncthreads();   // drains vmcnt(0) incl. global_load_lds

    // ---- wave (wy,wx): rows wy*64+[0,64), cols wx*64+[0,64) (one m) ----
    const int l15 = lane & 15, q = lane >> 4, xr = l15 & 7;
    const int wy = w >> 1, wx = w & 1;
    const int rbase = wy * 64, cbase = wx * 64;
    const int m = (cb << 1) + wx;
    const float hinvL = (0.5f / var[0]) * 1.44269504088896f;  // 0.5/var * log2(e)
    const float h2L   = hinvL + hinvL;

    // c-side factors + B-fragments (loaded once)
    f32x4 nbh[4];
    i32x8 b8v[4];
    #pragma unroll
    for (int jc = 0; jc < 4; ++jc) {
        const f32x4 bv = *(const f32x4*)&b2s[cbase + jc * 16 + q * 4];
        nbh[jc] = -bv * hinvL;
        const int ro = (cbase + jc * 16 + l15) * DD;
        const i32x4 lo = *(const i32x4*)&Bs[ro + (((q << 1) | 0) ^ xr) * 16];
        const i32x4 hi = *(const i32x4*)&Bs[ro + (((q << 1) | 1) ^ xr) * 16];
        #pragma unroll
        for (int e = 0; e < 4; ++e) { b8v[jc][e] = lo[e]; b8v[jc][4 + e] = hi[e]; }
    }

    // A fragments: lane holds A[rbase+i*16+l15][q*32 .. q*32+31]
    i32x8 a8[4];
    #pragma unroll
    for (int i = 0; i < 4; ++i) {
        const int ro = (rbase + i * 16 + l15) * DD;
        const i32x4 lo = *(const i32x4*)&As[ro + (((q << 1) | 0) ^ xr) * 16];
        const i32x4 hi = *(const i32x4*)&As[ro + (((q << 1) | 1) ^ xr) * 16];
        #pragma unroll
        for (int e = 0; e < 4; ++e) { a8[i][e] = lo[e]; a8[i][4 + e] = hi[e]; }
    }

    // Swapped operands -> c-reduction in-register. 16 MFMAs, pure-register.
    f32x4 acc[4][4] = {};
    __builtin_amdgcn_s_setprio(1);
    #pragma unroll
    for (int jc = 0; jc < 4; ++jc)
        #pragma unroll
        for (int i = 0; i < 4; ++i)
            acc[jc][i] = __builtin_amdgcn_mfma_scale_f32_16x16x128_f8f6f4(
                            b8v[jc], a8[i], acc[jc][i],
                            0, 0,          // cbsz=0 (fp8), blgp=0 (fp8)
                            0, 127,        // scale_a = 1.0
                            0, 127);       // scale_b = 1.0
    __builtin_amdgcn_s_setprio(0);

    // epilogue: dens = exp2(log2e*(2ab - a2 - b2)*0.5/var);
    // 16 c lane-local -> 2 partial chains + 4-way over q (2 shfl_xor).
    float sums[4];
    #pragma unroll
    for (int i = 0; i < 4; ++i) {
        const float aih = a2s[rbase + i * 16 + l15] * hinvL;
        float s0 = 0.f, s1 = 0.f;
        #pragma unroll
        for (int jc = 0; jc < 4; jc += 2) {
            #pragma unroll
            for (int r = 0; r < 4; ++r) {
                s0 += __builtin_amdgcn_exp2f(fmaf(h2L, acc[jc][i][r],     nbh[jc][r]     - aih));
                s1 += __builtin_amdgcn_exp2f(fmaf(h2L, acc[jc + 1][i][r], nbh[jc + 1][r] - aih));
            }
        }
        float s = s0 + s1;
        s += __shfl_xor(s, 16, 64);
        s += __shfl_xor(s, 32, 64);
        sums[i] = s;   // full 64-col sum for n = rbase + i*16 + l15
    }
    // lane owns n = rbase + lane (i == q); static select; coalesced store
    const float v01 = (q & 1) ? sums[1] : sums[0];
    const float v23 = (q & 1) ? sums[3] : sums[2];
    const float myv = (q & 2) ? v23 : v01;
    dpc[(size_t)m * NN + n0 + rbase + lane] = myv;
}

// ---- normalize: out[n,m] = dpc[m,n] / (sum_m dpc[:,n] + 1e-10) ----
// 256 blocks x 16 n each (4x round-0 parallelism); m-ascending sum order.
__global__ __launch_bounds__(256)
void kde_norm_kernel(const float* __restrict__ dpc, float* __restrict__ out)
{
    __shared__ float tile[128][17];    // [m][nloc], odd stride
    __shared__ float rden[16];
    const int n0 = blockIdx.x * 16;
    const int t  = threadIdx.x;

    const int mr = t >> 1, half = t & 1;   // 128 rows x 2 threads
    {
        const float4 va = *(const float4*)&dpc[(size_t)mr * NN + n0 + half * 8];
        const float4 vb = *(const float4*)&dpc[(size_t)mr * NN + n0 + half * 8 + 4];
        float* tr = &tile[mr][half * 8];
        tr[0] = va.x; tr[1] = va.y; tr[2] = va.z; tr[3] = va.w;
        tr[4] = vb.x; tr[5] = vb.y; tr[6] = vb.z; tr[7] = vb.w;
    }
    __syncthreads();

    if (t < 16) {
        float s = 0.f;
        #pragma unroll 8
        for (int mm = 0; mm < MM; ++mm) s += tile[mm][t];   // m ascending, matches ref
        rden[t] = 1.f / (s + 1e-10f);
    }
    __syncthreads();

    const int j = t >> 4, m0 = (t & 15) * 8;
    const float r = rden[j];
    float4 o0, o1;
    o0.x = tile[m0][j] * r;     o0.y = tile[m0 + 1][j] * r;
    o0.z = tile[m0 + 2][j] * r; o0.w = tile[m0 + 3][j] * r;
    o1.x = tile[m0 + 4][j] * r; o1.y = tile[m0 + 5][j] * r;
    o1.z = tile[m0 + 6][j] * r; o1.w = tile[m0 + 7][j] * r;
    float* obase = &out[(size_t)(n0 + j) * MM + m0];
    *(float4*)obase       = o0;
    *(float4*)(obase + 4) = o1;   // 512B per 16-thread group, coalesced
}

extern "C" void kernel_launch(void* const* d_in, const int* in_sizes, int n_in,
                              void* d_out, int out_size, void* d_ws, size_t ws_size,
                              hipStream_t stream) {
    const float* A   = (const float*)d_in[0];   // [4096][128]
    const float* B   = (const float*)d_in[1];   // [128][64][128] = [8192][128]
    const float* var = (const float*)d_in[2];   // [1]
    float* out = (float*)d_out;                 // [4096][128]

    unsigned char* A8 = (unsigned char*)d_ws;            // 512 KB
    unsigned char* B8 = A8 + (size_t)NN * DD;            // 1 MB
    float* a2  = (float*)(B8 + (size_t)CC * DD);         // 16 KB
    float* b2  = a2 + NN;                                // 32 KB
    float* dpc = b2 + CC;                                // 2 MB, [MM][NN]

    prep_kernel<<<(NN + CC) / 8, 256, 0, stream>>>(A, B, A8, B8, a2, b2);
    kde_dens_kernel<<<2048, 256, 0, stream>>>(A8, B8, var, a2, b2, dpc);
    kde_norm_kernel<<<NN / 16, 256, 0, stream>>>(dpc, out);
}